// Round 6
// baseline (3967.694 us; speedup 1.0000x reference)
//
#include <hip/hip_runtime.h>
#include <math.h>

#define BB 64
#define TT 128
#define SS 256
#define HHH 1024
#define SCANBLK 64

typedef unsigned short u16;
typedef unsigned long long u64t;
typedef __bf16 bf16x8 __attribute__((ext_vector_type(8)));
typedef float f32x4 __attribute__((ext_vector_type(4)));
typedef u16 u16x8 __attribute__((ext_vector_type(8)));

__device__ __forceinline__ float sigmoidf_(float x) { return 1.0f / (1.0f + expf(-x)); }
__device__ __forceinline__ u16 f2bf(float f) {
    __bf16 h = (__bf16)f;
    return __builtin_bit_cast(u16, h);
}
__device__ __forceinline__ float b2f(u16 u) {
    return __builtin_bit_cast(float, (unsigned)u << 16);
}
template <typename OT>
__device__ __forceinline__ void stout(OT* p, float v) {
    if constexpr (sizeof(OT) == 2) *p = f2bf(v); else *p = v;
}
__device__ __forceinline__ u64t aload(const u64t* p) {
    return __hip_atomic_load(p, __ATOMIC_RELAXED, __HIP_MEMORY_SCOPE_AGENT);
}
__device__ __forceinline__ void astore(u64t* p, u64t v) {
    __hip_atomic_store(p, v, __ATOMIC_RELAXED, __HIP_MEMORY_SCOPE_AGENT);
}

// ---------------------------------------------------------------------------
// fp32 → bf16 elementwise
// ---------------------------------------------------------------------------
__global__ __launch_bounds__(256) void f32_to_bf16(const float* __restrict__ in,
                                                   u16* __restrict__ out, long n) {
    long i = ((long)blockIdx.x * 256 + threadIdx.x) * 8;
    float4 a = *(const float4*)(in + i);
    float4 b = *(const float4*)(in + i + 4);
    u16x8 o;
    o[0] = f2bf(a.x); o[1] = f2bf(a.y); o[2] = f2bf(a.z); o[3] = f2bf(a.w);
    o[4] = f2bf(b.x); o[5] = f2bf(b.y); o[6] = f2bf(b.z); o[7] = f2bf(b.w);
    *(u16x8*)(out + i) = o;
}

// ---------------------------------------------------------------------------
// W_hh [row=g*1024+j][1024] fp32 -> Whi/Wlo bf16 [row'=j*4+g][1024]
// ---------------------------------------------------------------------------
__global__ __launch_bounds__(256) void split_whh(const float* __restrict__ W,
                                                 u16* __restrict__ hi,
                                                 u16* __restrict__ lo) {
    const int row = blockIdx.x;            // 0..4095 source row
    const int g = row >> 10, j = row & 1023;
    const int dst = (j << 2) | g;
    const int k4 = threadIdx.x << 2;
    float4 v = *(const float4*)(W + (size_t)row * 1024 + k4);
    u16 h0 = f2bf(v.x), h1 = f2bf(v.y), h2 = f2bf(v.z), h3 = f2bf(v.w);
    ushort4 hv = {h0, h1, h2, h3};
    ushort4 lv = {f2bf(v.x - b2f(h0)), f2bf(v.y - b2f(h1)),
                  f2bf(v.z - b2f(h2)), f2bf(v.w - b2f(h3))};
    *(ushort4*)(hi + (size_t)dst * 1024 + k4) = hv;
    *(ushort4*)(lo + (size_t)dst * 1024 + k4) = lv;
}

// ---------------------------------------------------------------------------
// h0 [64 b][1024 j] fp32 -> hhi/hlo bf16 (same [b][j] layout)
// ---------------------------------------------------------------------------
__global__ __launch_bounds__(256) void h0_split(const float* __restrict__ h0,
                                                u16* __restrict__ hi,
                                                u16* __restrict__ lo) {
    long i = ((long)blockIdx.x * 256 + threadIdx.x) * 4;
    float4 v = *(const float4*)(h0 + i);
    u16 a0 = f2bf(v.x), a1 = f2bf(v.y), a2 = f2bf(v.z), a3 = f2bf(v.w);
    ushort4 hv = {a0, a1, a2, a3};
    ushort4 lv = {f2bf(v.x - b2f(a0)), f2bf(v.y - b2f(a1)),
                  f2bf(v.z - b2f(a2)), f2bf(v.w - b2f(a3))};
    *(ushort4*)(hi + i) = hv;
    *(ushort4*)(lo + i) = lv;
}

// ---------------------------------------------------------------------------
// MFMA bf16 GEMM (A@B^T). XGT mode: logical A row r=t*64+b (phys (r&63)*128+(r>>6));
// C written fp32 to xgt[t][r'=j*4+g][b] with (b_ih+b_hh) folded.
// ---------------------------------------------------------------------------
template <bool TANH, bool XGT, typename OT>
__global__ __launch_bounds__(256) void gemm_mfma_bt(
    const u16* __restrict__ A0, const u16* __restrict__ A1,
    const u16* __restrict__ B, OT* __restrict__ C,
    int M, int N, int K, int KA0,
    const float* __restrict__ bias0, const float* __restrict__ bias1)
{
    __shared__ uint4 As4[512];
    __shared__ uint4 Bs4[512];
    u16* As = (u16*)As4;
    u16* Bs = (u16*)Bs4;
    const int tid = threadIdx.x;
    const int l = tid & 63;
    const int w = tid >> 6;
    const int wm = w >> 1, wn = w & 1;
    const int tc = l & 15, tr8 = (l >> 4) << 3;
    const int m0 = blockIdx.y << 7, n0 = blockIdx.x << 7;
    f32x4 acc[4][4] = {};

    for (int k0 = 0; k0 < K; k0 += 32) {
        const u16* Ap = (k0 < KA0) ? A0 : A1;
        const int koff = (k0 < KA0) ? k0 : k0 - KA0;
#pragma unroll
        for (int r = 0; r < 2; ++r) {
            int u = tid + (r << 8);
            int row = u >> 2, q = u & 3;
            size_t arow;
            if (XGT) {
                int rr = m0 + row;
                arow = (size_t)((rr & 63) * 128 + (rr >> 6));
            } else {
                arow = (size_t)(m0 + row);
            }
            As4[u] = *(const uint4*)(Ap + arow * KA0 + koff + (q << 3));
            Bs4[u] = *(const uint4*)(B + (size_t)(n0 + row) * K + k0 + (q << 3));
        }
        __syncthreads();
        bf16x8 bfr[4];
#pragma unroll
        for (int j = 0; j < 4; ++j)
            bfr[j] = *(const bf16x8*)(Bs + ((wn << 6) + (j << 4) + tc) * 32 + tr8);
#pragma unroll
        for (int i = 0; i < 4; ++i) {
            bf16x8 af = *(const bf16x8*)(As + ((wm << 6) + (i << 4) + tc) * 32 + tr8);
#pragma unroll
            for (int j = 0; j < 4; ++j)
                acc[i][j] = __builtin_amdgcn_mfma_f32_16x16x32_bf16(af, bfr[j], acc[i][j], 0, 0, 0);
        }
        __syncthreads();
    }
#pragma unroll
    for (int j = 0; j < 4; ++j) {
        const int col = n0 + (wn << 6) + (j << 4) + tc;
        const float bias = XGT ? (bias0[col] + bias1[col]) : 0.0f;
#pragma unroll
        for (int i = 0; i < 4; ++i) {
#pragma unroll
            for (int v = 0; v < 4; ++v) {
                int r = m0 + (wm << 6) + (i << 4) + ((l >> 4) << 2) + v;
                float val = acc[i][j][v];
                if (XGT) {
                    int newr = ((col & 1023) << 2) | (col >> 10);   // j*4+g
                    ((float*)C)[(size_t)(r >> 6) * 262144 + (size_t)newr * 64 + (r & 63)] = val + bias;
                } else {
                    if (TANH) val = tanhf(val);
                    stout(&C[(size_t)r * N + col], val);
                }
            }
        }
    }
}

// ---------------------------------------------------------------------------
// Persistent LSTM scan. 64 blocks x 256 thr (4 waves), all 128 steps inside.
// Block owns 16 j x 4 gates = 64 W-rows for all 64 b; wave = K-quarter.
// gates = Whi@hhi + Whi@hlo + Wlo@hhi (same math as round 5, bit-identical).
// h exchanged cross-XCD via agent-scope RELAXED atomic 8B ops (sc1: bypass
// the non-coherent local L2, served by the coherent memory side / L3 — no
// L2 writeback/invalidate ever). W/xgt immutable -> normal cached loads.
// Barrier: monotonic relaxed-atomic counter; __syncthreads()'s implicit
// vmcnt(0) drain before arrival orders the h stores. c lives in registers.
// ---------------------------------------------------------------------------
__global__ __launch_bounds__(256) void lstm_scan64(
    const float* __restrict__ xgt,
    const u16* __restrict__ Whi, const u16* __restrict__ Wlo,
    const float* __restrict__ c0,
    u16* __restrict__ hEhi, u16* __restrict__ hElo,
    u16* __restrict__ hOhi, u16* __restrict__ hOlo,
    float* __restrict__ hT, float* __restrict__ cT,
    u16* __restrict__ lstm16, int* __restrict__ cnt)
{
    __shared__ float red[4][64][68];                    // 69.6 KB
    __shared__ __align__(16) u16 tileh[64][16];         // h-hi transpose tile
    __shared__ __align__(16) u16 tilel[64][16];
    const int tid = threadIdx.x;
    const int kg = tid >> 6, l = tid & 63;
    const int tc = l & 15, tr8 = (l >> 4) << 3;
    const int r0 = blockIdx.x << 6;    // 64 gate-rows
    const int j0 = blockIdx.x << 4;    // 16 j
    const int kbase = kg << 8;
    const int bb = tid & 63;           // epilogue batch (same for all p)

    float cv[4];
#pragma unroll
    for (int p = 0; p < 4; ++p) {
        int jl = (tid >> 6) + p * 4;
        cv[p] = c0[(size_t)bb * 1024 + j0 + jl];
    }

    for (int t = 0; t < 128; ++t) {
        const u16* ihi = (t & 1) ? hOhi : hEhi;
        const u16* ilo = (t & 1) ? hOlo : hElo;
        u16* ohi = (t & 1) ? hEhi : hOhi;
        u16* olo = (t & 1) ? hElo : hOlo;

        // xg gate values for this step (independent of h; coalesced dwords)
        float xgv[4][4];
#pragma unroll
        for (int p = 0; p < 4; ++p) {
            int jl = (tid >> 6) + p * 4;
#pragma unroll
            for (int g = 0; g < 4; ++g)
                xgv[p][g] = xgt[(size_t)t * 262144 + (size_t)((j0 + jl) * 4 + g) * 64 + bb];
        }

        f32x4 acc[4][4] = {};
#pragma unroll 2
        for (int ks = 0; ks < 8; ++ks) {
            const int k = kbase + ks * 32 + tr8;
            bf16x8 ahi[4], alo[4], bhi[4], blo[4];
#pragma unroll
            for (int rt = 0; rt < 4; ++rt) {
                ahi[rt] = *(const bf16x8*)(Whi + (size_t)(r0 + rt * 16 + tc) * 1024 + k);
                alo[rt] = *(const bf16x8*)(Wlo + (size_t)(r0 + rt * 16 + tc) * 1024 + k);
            }
#pragma unroll
            for (int bt = 0; bt < 4; ++bt) {
                size_t e = ((size_t)(bt * 16 + tc) * 1024 + k) >> 2;   // 8B index
                union { u64t u[2]; bf16x8 v; } th, tl2;
                th.u[0] = aload((const u64t*)ihi + e);
                th.u[1] = aload((const u64t*)ihi + e + 1);
                tl2.u[0] = aload((const u64t*)ilo + e);
                tl2.u[1] = aload((const u64t*)ilo + e + 1);
                bhi[bt] = th.v;
                blo[bt] = tl2.v;
            }
#pragma unroll
            for (int rt = 0; rt < 4; ++rt)
#pragma unroll
                for (int bt = 0; bt < 4; ++bt) {
                    acc[rt][bt] = __builtin_amdgcn_mfma_f32_16x16x32_bf16(ahi[rt], bhi[bt], acc[rt][bt], 0, 0, 0);
                    acc[rt][bt] = __builtin_amdgcn_mfma_f32_16x16x32_bf16(ahi[rt], blo[bt], acc[rt][bt], 0, 0, 0);
                    acc[rt][bt] = __builtin_amdgcn_mfma_f32_16x16x32_bf16(alo[rt], bhi[bt], acc[rt][bt], 0, 0, 0);
                }
        }
#pragma unroll
        for (int rt = 0; rt < 4; ++rt)
#pragma unroll
            for (int bt = 0; bt < 4; ++bt)
#pragma unroll
                for (int v = 0; v < 4; ++v)
                    red[kg][rt * 16 + (l >> 4) * 4 + v][bt * 16 + tc] = acc[rt][bt][v];
        __syncthreads();

        // epilogue: thread -> (b=bb, 4 j's)
#pragma unroll
        for (int p = 0; p < 4; ++p) {
            int jl = (tid >> 6) + p * 4;
            float gate[4];
#pragma unroll
            for (int g = 0; g < 4; ++g) {
                int rr = jl * 4 + g;
                gate[g] = red[0][rr][bb] + red[1][rr][bb] +
                          red[2][rr][bb] + red[3][rr][bb] + xgv[p][g];
            }
            float ii = sigmoidf_(gate[0]);
            float ff = sigmoidf_(gate[1]);
            float gg = tanhf(gate[2]);
            float oo = sigmoidf_(gate[3]);
            float cn = ff * cv[p] + ii * gg;
            float hn = oo * tanhf(cn);
            cv[p] = cn;
            u16 hh = f2bf(hn);
            tileh[bb][jl] = hh;
            tilel[bb][jl] = f2bf(hn - b2f(hh));
            if (t == 127) {
                hT[(size_t)bb * 1024 + j0 + jl] = hn;
                cT[(size_t)bb * 1024 + j0 + jl] = cn;
            }
        }
        __syncthreads();

        // coalesced-row store of the block's h slice + lstm_out
        if (tid < 64) {
            const u64t* src = (const u64t*)&tileh[tid][0];
            size_t e = ((size_t)tid * 1024 + j0) >> 2;
#pragma unroll
            for (int q = 0; q < 4; ++q) astore((u64t*)ohi + e + q, src[q]);
            uint4* dst = (uint4*)(lstm16 + ((size_t)tid * 128 + t) * 1024 + j0);
            dst[0] = ((const uint4*)src)[0];
            dst[1] = ((const uint4*)src)[1];
        } else if (tid < 128) {
            int b = tid - 64;
            const u64t* src = (const u64t*)&tilel[b][0];
            size_t e = ((size_t)b * 1024 + j0) >> 2;
#pragma unroll
            for (int q = 0; q < 4; ++q) astore((u64t*)olo + e + q, src[q]);
        }

        // grid barrier: syncthreads drains every wave's vmem (incl. the
        // atomic h-stores) before lane 0 announces arrival.
        if (t < 127) {
            __syncthreads();
            if (tid == 0) {
                __hip_atomic_fetch_add(cnt, 1, __ATOMIC_RELAXED, __HIP_MEMORY_SCOPE_AGENT);
                const int target = SCANBLK * (t + 1);
                while (__hip_atomic_load(cnt, __ATOMIC_RELAXED, __HIP_MEMORY_SCOPE_AGENT) < target)
                    __builtin_amdgcn_s_sleep(2);
            }
            __syncthreads();
            asm volatile("" ::: "memory");
        }
    }
}

// ---------------------------------------------------------------------------
// fp32 GEMM C = A @ B^T (scores), batched via blockIdx.z.
// ---------------------------------------------------------------------------
template <int BM, int BN, int TM, int TN>
__global__ __launch_bounds__(256) void gemm_bt(
    const float* __restrict__ A, const float* __restrict__ Bm, float* __restrict__ C,
    int M, int N, int K, long sA, long sB, long sC)
{
    constexpr int BK = 16;
    __shared__ float As[BK][BM + 1];
    __shared__ float Bs[BK][BN + 1];
    const int z = blockIdx.z;
    A += (long)z * sA; Bm += (long)z * sB; C += (long)z * sC;
    const int bm = blockIdx.y * BM, bn = blockIdx.x * BN;
    const int tid = threadIdx.x;
    constexpr int TC = BN / TN;
    const int tc = tid % TC, tr = tid / TC;
    float acc[TM][TN] = {};
    for (int k0 = 0; k0 < K; k0 += BK) {
        for (int i = tid; i < BM * 4; i += 256) {
            int m = i >> 2, k4 = (i & 3) << 2;
            float4 v = *(const float4*)(A + (long)(bm + m) * K + k0 + k4);
            As[k4][m] = v.x; As[k4 + 1][m] = v.y; As[k4 + 2][m] = v.z; As[k4 + 3][m] = v.w;
        }
        for (int i = tid; i < BN * 4; i += 256) {
            int n = i >> 2, k4 = (i & 3) << 2;
            float4 v = *(const float4*)(Bm + (long)(bn + n) * K + k0 + k4);
            Bs[k4][n] = v.x; Bs[k4 + 1][n] = v.y; Bs[k4 + 2][n] = v.z; Bs[k4 + 3][n] = v.w;
        }
        __syncthreads();
#pragma unroll
        for (int kk = 0; kk < BK; ++kk) {
            float a[TM], b[TN];
#pragma unroll
            for (int i = 0; i < TM; i++) a[i] = As[kk][tr * TM + i];
#pragma unroll
            for (int j = 0; j < TN; j++) b[j] = Bs[kk][tc * TN + j];
#pragma unroll
            for (int i = 0; i < TM; i++)
#pragma unroll
                for (int j = 0; j < TN; j++) acc[i][j] += a[i] * b[j];
        }
        __syncthreads();
    }
#pragma unroll
    for (int i = 0; i < TM; i++) {
        int m = bm + tr * TM + i;
#pragma unroll
        for (int j = 0; j < TN; j++) {
            int n = bn + tc * TN + j;
            C[(long)m * N + n] = acc[i][j];
        }
    }
}

// ---------------------------------------------------------------------------
// fp32 GEMM C = A @ B (context = attn @ ctx), OT output.
// ---------------------------------------------------------------------------
template <int BM, int BN, int TM, int TN, typename OT>
__global__ __launch_bounds__(256) void gemm_bn(
    const float* __restrict__ A, const float* __restrict__ Bm, OT* __restrict__ C,
    int M, int N, int K, long sA, long sB, long sC)
{
    constexpr int BK = 16;
    __shared__ float As[BK][BM + 1];
    __shared__ float Bs[BK][BN + 1];
    const int z = blockIdx.z;
    A += (long)z * sA; Bm += (long)z * sB; C += (long)z * sC;
    const int bm = blockIdx.y * BM, bn = blockIdx.x * BN;
    const int tid = threadIdx.x;
    constexpr int TC = BN / TN;
    const int tc = tid % TC, tr = tid / TC;
    float acc[TM][TN] = {};
    for (int k0 = 0; k0 < K; k0 += BK) {
        for (int i = tid; i < BM * 4; i += 256) {
            int m = i >> 2, k4 = (i & 3) << 2;
            float4 v = *(const float4*)(A + (long)(bm + m) * K + k0 + k4);
            As[k4][m] = v.x; As[k4 + 1][m] = v.y; As[k4 + 2][m] = v.z; As[k4 + 3][m] = v.w;
        }
        for (int i = tid; i < BK * (BN / 4); i += 256) {
            int k = i / (BN / 4), n4 = (i % (BN / 4)) * 4;
            float4 v = *(const float4*)(Bm + (long)(k0 + k) * N + bn + n4);
            Bs[k][n4] = v.x; Bs[k][n4 + 1] = v.y; Bs[k][n4 + 2] = v.z; Bs[k][n4 + 3] = v.w;
        }
        __syncthreads();
#pragma unroll
        for (int kk = 0; kk < BK; ++kk) {
            float a[TM], b[TN];
#pragma unroll
            for (int i = 0; i < TM; i++) a[i] = As[kk][tr * TM + i];
#pragma unroll
            for (int j = 0; j < TN; j++) b[j] = Bs[kk][tc * TN + j];
#pragma unroll
            for (int i = 0; i < TM; i++)
#pragma unroll
                for (int j = 0; j < TN; j++) acc[i][j] += a[i] * b[j];
        }
        __syncthreads();
    }
#pragma unroll
    for (int i = 0; i < TM; i++) {
        int m = bm + tr * TM + i;
#pragma unroll
        for (int j = 0; j < TN; j++) {
            int n = bn + tc * TN + j;
            stout(&C[(long)m * N + n], acc[i][j]);
        }
    }
}

// ---------------------------------------------------------------------------
// Masked softmax over S=256, in place.
// ---------------------------------------------------------------------------
__global__ __launch_bounds__(256) void softmax_mask(
    float* __restrict__ attn, const int* __restrict__ src_len)
{
    __shared__ float red[4];
    const int b = blockIdx.y, t = blockIdx.x, s = threadIdx.x;
    float* row = attn + ((long)b * TT + t) * SS;
    const int L = src_len[b];
    float v = (s < L) ? row[s] : -INFINITY;
    float m = v;
#pragma unroll
    for (int o = 32; o >= 1; o >>= 1) m = fmaxf(m, __shfl_xor(m, o));
    if ((s & 63) == 0) red[s >> 6] = m;
    __syncthreads();
    m = fmaxf(fmaxf(red[0], red[1]), fmaxf(red[2], red[3]));
    __syncthreads();
    float e = (s < L) ? expf(v - m) : 0.0f;
    float sum = e;
#pragma unroll
    for (int o = 32; o >= 1; o >>= 1) sum += __shfl_xor(sum, o);
    if ((s & 63) == 0) red[s >> 6] = sum;
    __syncthreads();
    sum = red[0] + red[1] + red[2] + red[3];
    row[s] = e / sum;
}

// ---------------------------------------------------------------------------
extern "C" void kernel_launch(void* const* d_in, const int* in_sizes, int n_in,
                              void* d_out, int out_size, void* d_ws, size_t ws_size,
                              hipStream_t stream)
{
    const float* trg_emb = (const float*)d_in[0];
    const float* h0      = (const float*)d_in[1];
    const float* c0      = (const float*)d_in[2];
    const float* ctx     = (const float*)d_in[3];
    const int*   src_len = (const int*)d_in[4];
    const float* W_ih    = (const float*)d_in[5];
    const float* W_hh    = (const float*)d_in[6];
    const float* b_ih    = (const float*)d_in[7];
    const float* b_hh    = (const float*)d_in[8];
    const float* W_in    = (const float*)d_in[9];
    const float* W_out   = (const float*)d_in[10];

    float* out = (float*)d_out;
    float* h_tilde = out;                          // [B,T,H]
    float* hT = out + (size_t)BB * TT * HHH;       // [1,B,H]
    float* cT = hT + (size_t)BB * HHH;             // [1,B,H]

    char* w = (char*)d_ws;
    auto take = [&](size_t bytes) { void* p = w; w += (bytes + 255) & ~(size_t)255; return p; };
    u16* trg16  = (u16*)take(8388608ull * 2);
    u16* Wih16  = (u16*)take(4194304ull * 2);
    u16* Win16  = (u16*)take(1048576ull * 2);
    u16* Wout16 = (u16*)take(2097152ull * 2);
    u16* lstm16 = (u16*)take(8388608ull * 2);
    u16* Whi    = (u16*)take(4194304ull * 2);
    u16* Wlo    = (u16*)take(4194304ull * 2);
    u16* hEhi   = (u16*)take(65536ull * 2);
    u16* hElo   = (u16*)take(65536ull * 2);
    u16* hOhi   = (u16*)take(65536ull * 2);
    u16* hOlo   = (u16*)take(65536ull * 2);
    int* bar    = (int*)take(256);
    char* regionB = w;
    float* xgt = (float*)take(33554432ull * 4);    // [t][4H r=j*4+g][B] fp32
    float* q        = (float*)regionB;
    float* attn     = (float*)(regionB + 33554432ull);
    u16*   ctxout16 = (u16*)(regionB + 41943040ull);

    // barrier counter must start at 0 every call (ws is poisoned once)
    hipMemsetAsync(bar, 0, 256, stream);

    // prep (independent, parallel)
    f32_to_bf16<<<4096, 256, 0, stream>>>(trg_emb, trg16, 8388608);
    f32_to_bf16<<<2048, 256, 0, stream>>>(W_ih, Wih16, 4194304);
    f32_to_bf16<<<512, 256, 0, stream>>>(W_in, Win16, 1048576);
    f32_to_bf16<<<1024, 256, 0, stream>>>(W_out, Wout16, 2097152);
    split_whh<<<4096, 256, 0, stream>>>(W_hh, Whi, Wlo);
    h0_split<<<64, 256, 0, stream>>>(h0, hEhi, hElo);

    // x_gates = trg_emb @ W_ih^T + (b_ih+b_hh) -> fp32 xgt[t][j*4+g][b]
    gemm_mfma_bt<false, true, float><<<dim3(32, 64), 256, 0, stream>>>(
        trg16, trg16, Wih16, xgt, 8192, 4096, 1024, 1024, b_ih, b_hh);

    // persistent LSTM scan (single launch; writes lstm16, hT, cT)
    lstm_scan64<<<SCANBLK, 256, 0, stream>>>(xgt, Whi, Wlo, c0,
                                             hEhi, hElo, hOhi, hOlo,
                                             hT, cT, lstm16, bar);

    // q = lstm_out @ W_in^T (bf16 MFMA, fp32 out)
    gemm_mfma_bt<false, false, float><<<dim3(8, 64), 256, 0, stream>>>(
        lstm16, lstm16, Win16, q, 8192, 1024, 1024, 1024, nullptr, nullptr);

    // scores[b] = q[b] @ ctx[b]^T (fp32)
    gemm_bt<64, 64, 4, 4><<<dim3(4, 2, 64), 256, 0, stream>>>(
        q, ctx, attn, TT, SS, HHH,
        (long)TT * HHH, (long)SS * HHH, (long)TT * SS);

    softmax_mask<<<dim3(TT, BB, 1), 256, 0, stream>>>(attn, src_len);

    // context[b] = attn[b] @ ctx[b] (fp32 compute, bf16 out)
    gemm_bn<64, 64, 4, 4, u16><<<dim3(16, 2, 64), 256, 0, stream>>>(
        attn, ctx, ctxout16, TT, HHH, SS,
        (long)TT * SS, (long)SS * HHH, (long)TT * HHH);

    // h_tilde = tanh([context, lstm_out] @ W_out^T)
    gemm_mfma_bt<true, false, float><<<dim3(8, 64), 256, 0, stream>>>(
        ctxout16, lstm16, Wout16, h_tilde, 8192, 1024, 2048, 1024, nullptr, nullptr);
}

// Round 7
// 2997.710 us; speedup vs baseline: 1.3236x; 1.3236x over previous
//
#include <hip/hip_runtime.h>
#include <math.h>

#define BB 64
#define TT 128
#define SS 256
#define HHH 1024
#define SCANBLK 256

typedef unsigned short u16;
typedef unsigned long long u64t;
typedef __bf16 bf16x8 __attribute__((ext_vector_type(8)));
typedef float f32x4 __attribute__((ext_vector_type(4)));
typedef u16 u16x8 __attribute__((ext_vector_type(8)));

__device__ __forceinline__ float sigmoidf_(float x) { return 1.0f / (1.0f + expf(-x)); }
__device__ __forceinline__ u16 f2bf(float f) {
    __bf16 h = (__bf16)f;
    return __builtin_bit_cast(u16, h);
}
__device__ __forceinline__ float b2f(u16 u) {
    return __builtin_bit_cast(float, (unsigned)u << 16);
}
template <typename OT>
__device__ __forceinline__ void stout(OT* p, float v) {
    if constexpr (sizeof(OT) == 2) *p = f2bf(v); else *p = v;
}
__device__ __forceinline__ u64t aload(const u64t* p) {
    return __hip_atomic_load(p, __ATOMIC_RELAXED, __HIP_MEMORY_SCOPE_AGENT);
}
__device__ __forceinline__ void astore(u64t* p, u64t v) {
    __hip_atomic_store(p, v, __ATOMIC_RELAXED, __HIP_MEMORY_SCOPE_AGENT);
}

// ---------------------------------------------------------------------------
// fp32 → bf16 elementwise
// ---------------------------------------------------------------------------
__global__ __launch_bounds__(256) void f32_to_bf16(const float* __restrict__ in,
                                                   u16* __restrict__ out, long n) {
    long i = ((long)blockIdx.x * 256 + threadIdx.x) * 8;
    float4 a = *(const float4*)(in + i);
    float4 b = *(const float4*)(in + i + 4);
    u16x8 o;
    o[0] = f2bf(a.x); o[1] = f2bf(a.y); o[2] = f2bf(a.z); o[3] = f2bf(a.w);
    o[4] = f2bf(b.x); o[5] = f2bf(b.y); o[6] = f2bf(b.z); o[7] = f2bf(b.w);
    *(u16x8*)(out + i) = o;
}

// ---------------------------------------------------------------------------
// W_hh [row=g*1024+j][1024] fp32 -> Whi/Wlo bf16 [row'=j*4+g][1024]
// ---------------------------------------------------------------------------
__global__ __launch_bounds__(256) void split_whh(const float* __restrict__ W,
                                                 u16* __restrict__ hi,
                                                 u16* __restrict__ lo) {
    const int row = blockIdx.x;            // 0..4095 source row
    const int g = row >> 10, j = row & 1023;
    const int dst = (j << 2) | g;
    const int k4 = threadIdx.x << 2;
    float4 v = *(const float4*)(W + (size_t)row * 1024 + k4);
    u16 h0 = f2bf(v.x), h1 = f2bf(v.y), h2 = f2bf(v.z), h3 = f2bf(v.w);
    ushort4 hv = {h0, h1, h2, h3};
    ushort4 lv = {f2bf(v.x - b2f(h0)), f2bf(v.y - b2f(h1)),
                  f2bf(v.z - b2f(h2)), f2bf(v.w - b2f(h3))};
    *(ushort4*)(hi + (size_t)dst * 1024 + k4) = hv;
    *(ushort4*)(lo + (size_t)dst * 1024 + k4) = lv;
}

// ---------------------------------------------------------------------------
// h0 [64 b][1024 j] fp32 -> hhi/hlo bf16 (same [b][j] layout)
// ---------------------------------------------------------------------------
__global__ __launch_bounds__(256) void h0_split(const float* __restrict__ h0,
                                                u16* __restrict__ hi,
                                                u16* __restrict__ lo) {
    long i = ((long)blockIdx.x * 256 + threadIdx.x) * 4;
    float4 v = *(const float4*)(h0 + i);
    u16 a0 = f2bf(v.x), a1 = f2bf(v.y), a2 = f2bf(v.z), a3 = f2bf(v.w);
    ushort4 hv = {a0, a1, a2, a3};
    ushort4 lv = {f2bf(v.x - b2f(a0)), f2bf(v.y - b2f(a1)),
                  f2bf(v.z - b2f(a2)), f2bf(v.w - b2f(a3))};
    *(ushort4*)(hi + i) = hv;
    *(ushort4*)(lo + i) = lv;
}

// ---------------------------------------------------------------------------
// MFMA bf16 GEMM (A@B^T). XGT mode: logical A row r=t*64+b (phys (r&63)*128+(r>>6));
// C written fp32 to xgt[t][r'=j*4+g][b] with (b_ih+b_hh) folded.
// ---------------------------------------------------------------------------
template <bool TANH, bool XGT, typename OT>
__global__ __launch_bounds__(256) void gemm_mfma_bt(
    const u16* __restrict__ A0, const u16* __restrict__ A1,
    const u16* __restrict__ B, OT* __restrict__ C,
    int M, int N, int K, int KA0,
    const float* __restrict__ bias0, const float* __restrict__ bias1)
{
    __shared__ uint4 As4[512];
    __shared__ uint4 Bs4[512];
    u16* As = (u16*)As4;
    u16* Bs = (u16*)Bs4;
    const int tid = threadIdx.x;
    const int l = tid & 63;
    const int w = tid >> 6;
    const int wm = w >> 1, wn = w & 1;
    const int tc = l & 15, tr8 = (l >> 4) << 3;
    const int m0 = blockIdx.y << 7, n0 = blockIdx.x << 7;
    f32x4 acc[4][4] = {};

    for (int k0 = 0; k0 < K; k0 += 32) {
        const u16* Ap = (k0 < KA0) ? A0 : A1;
        const int koff = (k0 < KA0) ? k0 : k0 - KA0;
#pragma unroll
        for (int r = 0; r < 2; ++r) {
            int u = tid + (r << 8);
            int row = u >> 2, q = u & 3;
            size_t arow;
            if (XGT) {
                int rr = m0 + row;
                arow = (size_t)((rr & 63) * 128 + (rr >> 6));
            } else {
                arow = (size_t)(m0 + row);
            }
            As4[u] = *(const uint4*)(Ap + arow * KA0 + koff + (q << 3));
            Bs4[u] = *(const uint4*)(B + (size_t)(n0 + row) * K + k0 + (q << 3));
        }
        __syncthreads();
        bf16x8 bfr[4];
#pragma unroll
        for (int j = 0; j < 4; ++j)
            bfr[j] = *(const bf16x8*)(Bs + ((wn << 6) + (j << 4) + tc) * 32 + tr8);
#pragma unroll
        for (int i = 0; i < 4; ++i) {
            bf16x8 af = *(const bf16x8*)(As + ((wm << 6) + (i << 4) + tc) * 32 + tr8);
#pragma unroll
            for (int j = 0; j < 4; ++j)
                acc[i][j] = __builtin_amdgcn_mfma_f32_16x16x32_bf16(af, bfr[j], acc[i][j], 0, 0, 0);
        }
        __syncthreads();
    }
#pragma unroll
    for (int j = 0; j < 4; ++j) {
        const int col = n0 + (wn << 6) + (j << 4) + tc;
        const float bias = XGT ? (bias0[col] + bias1[col]) : 0.0f;
#pragma unroll
        for (int i = 0; i < 4; ++i) {
#pragma unroll
            for (int v = 0; v < 4; ++v) {
                int r = m0 + (wm << 6) + (i << 4) + ((l >> 4) << 2) + v;
                float val = acc[i][j][v];
                if (XGT) {
                    int newr = ((col & 1023) << 2) | (col >> 10);   // j*4+g
                    ((float*)C)[(size_t)(r >> 6) * 262144 + (size_t)newr * 64 + (r & 63)] = val + bias;
                } else {
                    if (TANH) val = tanhf(val);
                    stout(&C[(size_t)r * N + col], val);
                }
            }
        }
    }
}

// ---------------------------------------------------------------------------
// Persistent LSTM scan v3. 256 blocks x 512 thr (8 waves = 2/SIMD), 128 steps.
// Block owns 4 j x 4 gates = 16 W-rows for all 64 b; wave owns a 128-k slice,
// processed as 4 windows of k=32 with REGISTER double-buffered h fragments
// (16 x 8B agent-scope atomic loads issued one window ahead of the MFMAs).
// gates = Whi@hhi + Whi@hlo + Wlo@hhi (fp32-equivalent, same math as r5/r6).
// h exchanged via memory-side relaxed atomics (no L2 copies -> coherent, no
// wbinv). W/xgt immutable -> normal cached loads. c in registers.
// ---------------------------------------------------------------------------
__global__ __launch_bounds__(512) void lstm_scan512(
    const float* __restrict__ xgt,
    const u16* __restrict__ Whi, const u16* __restrict__ Wlo,
    const float* __restrict__ c0,
    u16* __restrict__ hEhi, u16* __restrict__ hElo,
    u16* __restrict__ hOhi, u16* __restrict__ hOlo,
    float* __restrict__ hT, float* __restrict__ cT,
    u16* __restrict__ lstm16, int* __restrict__ cnt)
{
    __shared__ float red[8][16][68];                 // 34.8 KB
    __shared__ __align__(8) u16 tileh[64][4];
    __shared__ __align__(8) u16 tilel[64][4];
    const int tid = threadIdx.x;
    const int kg = tid >> 6;           // wave 0..7 = 128-k slice
    const int l  = tid & 63;
    const int tc = l & 15, tr8 = (l >> 4) << 3;
    const int r0 = blockIdx.x << 4;    // 16 gate-rows
    const int j0 = blockIdx.x << 2;    // 4 j
    const int kbase = kg << 7;
    const int jl = tid >> 6;           // epilogue j (tid<256 only)
    const int b  = tid & 63;

    float creg = 0.0f;
    if (tid < 256) creg = c0[(size_t)b * 1024 + j0 + jl];

    for (int t = 0; t < 128; ++t) {
        const u16* ihi = (t & 1) ? hOhi : hEhi;
        const u16* ilo = (t & 1) ? hOlo : hElo;
        u16* ohi = (t & 1) ? hEhi : hOhi;
        u16* olo = (t & 1) ? hElo : hOlo;

        // xg gate values (cached loads, in flight through the MFMA phase)
        float xgv[4] = {};
        if (tid < 256) {
#pragma unroll
            for (int g = 0; g < 4; ++g)
                xgv[g] = xgt[(size_t)t * 262144 + (size_t)((j0 + jl) * 4 + g) * 64 + b];
        }

        // register double-buffered fragment windows
        bf16x8 ahi[2], alo[2], bhi[2][4], blo[2][4];
        auto loadwin = [&](int w, int s) {
            const int k = kbase + w * 32 + tr8;
            ahi[s] = *(const bf16x8*)(Whi + (size_t)(r0 + tc) * 1024 + k);
            alo[s] = *(const bf16x8*)(Wlo + (size_t)(r0 + tc) * 1024 + k);
#pragma unroll
            for (int bt = 0; bt < 4; ++bt) {
                size_t e = ((size_t)(bt * 16 + tc) * 1024 + k) >> 2;
                union { u64t u[2]; bf16x8 v; } th, tl2;
                th.u[0] = aload((const u64t*)ihi + e);
                th.u[1] = aload((const u64t*)ihi + e + 1);
                tl2.u[0] = aload((const u64t*)ilo + e);
                tl2.u[1] = aload((const u64t*)ilo + e + 1);
                bhi[s][bt] = th.v;
                blo[s][bt] = tl2.v;
            }
        };

        f32x4 acc[4] = {};
        loadwin(0, 0);
#pragma unroll
        for (int w = 0; w < 4; ++w) {
            const int s = w & 1;
            if (w < 3) loadwin(w + 1, s ^ 1);   // prefetch next window
#pragma unroll
            for (int bt = 0; bt < 4; ++bt) {
                acc[bt] = __builtin_amdgcn_mfma_f32_16x16x32_bf16(ahi[s], bhi[s][bt], acc[bt], 0, 0, 0);
                acc[bt] = __builtin_amdgcn_mfma_f32_16x16x32_bf16(ahi[s], blo[s][bt], acc[bt], 0, 0, 0);
                acc[bt] = __builtin_amdgcn_mfma_f32_16x16x32_bf16(alo[s], bhi[s][bt], acc[bt], 0, 0, 0);
            }
        }
#pragma unroll
        for (int bt = 0; bt < 4; ++bt)
#pragma unroll
            for (int v = 0; v < 4; ++v)
                red[kg][(l >> 4) * 4 + v][bt * 16 + tc] = acc[bt][v];
        __syncthreads();

        // epilogue: thread (jl, b), tid<256
        if (tid < 256) {
            float gate[4];
#pragma unroll
            for (int g = 0; g < 4; ++g) {
                int rr = jl * 4 + g;
                float s = 0.0f;
#pragma unroll
                for (int q = 0; q < 8; ++q) s += red[q][rr][b];
                gate[g] = s + xgv[g];
            }
            float ii = sigmoidf_(gate[0]);
            float ff = sigmoidf_(gate[1]);
            float gg = tanhf(gate[2]);
            float oo = sigmoidf_(gate[3]);
            float cn = ff * creg + ii * gg;
            float hn = oo * tanhf(cn);
            creg = cn;
            u16 hh = f2bf(hn);
            tileh[b][jl] = hh;
            tilel[b][jl] = f2bf(hn - b2f(hh));
            if (t == 127) {
                hT[(size_t)b * 1024 + j0 + jl] = hn;
                cT[(size_t)b * 1024 + j0 + jl] = cn;
            }
        }
        __syncthreads();

        // coalesced 8B h-out stores (memory-side) + lstm_out (normal)
        if (tid < 64) {
            u64t v = *(const u64t*)&tileh[tid][0];
            astore((u64t*)ohi + (((size_t)tid * 1024 + j0) >> 2), v);
            *(u64t*)(lstm16 + ((size_t)tid * 128 + t) * 1024 + j0) = v;
        } else if (tid < 128) {
            int bb = tid - 64;
            u64t v = *(const u64t*)&tilel[bb][0];
            astore((u64t*)olo + (((size_t)bb * 1024 + j0) >> 2), v);
        }

        // grid barrier: each wave's s_barrier is preceded by vmcnt(0), so all
        // h-stores are through the memory side before lane 0 announces.
        if (t < 127) {
            __syncthreads();
            if (tid == 0) {
                __hip_atomic_fetch_add(cnt, 1, __ATOMIC_RELAXED, __HIP_MEMORY_SCOPE_AGENT);
                const int target = SCANBLK * (t + 1);
                while (__hip_atomic_load(cnt, __ATOMIC_RELAXED, __HIP_MEMORY_SCOPE_AGENT) < target)
                    __builtin_amdgcn_s_sleep(2);
            }
            __syncthreads();
            asm volatile("" ::: "memory");
        }
    }
}

// ---------------------------------------------------------------------------
// fp32 GEMM C = A @ B^T (scores), batched via blockIdx.z.
// ---------------------------------------------------------------------------
template <int BM, int BN, int TM, int TN>
__global__ __launch_bounds__(256) void gemm_bt(
    const float* __restrict__ A, const float* __restrict__ Bm, float* __restrict__ C,
    int M, int N, int K, long sA, long sB, long sC)
{
    constexpr int BK = 16;
    __shared__ float As[BK][BM + 1];
    __shared__ float Bs[BK][BN + 1];
    const int z = blockIdx.z;
    A += (long)z * sA; Bm += (long)z * sB; C += (long)z * sC;
    const int bm = blockIdx.y * BM, bn = blockIdx.x * BN;
    const int tid = threadIdx.x;
    constexpr int TC = BN / TN;
    const int tc = tid % TC, tr = tid / TC;
    float acc[TM][TN] = {};
    for (int k0 = 0; k0 < K; k0 += BK) {
        for (int i = tid; i < BM * 4; i += 256) {
            int m = i >> 2, k4 = (i & 3) << 2;
            float4 v = *(const float4*)(A + (long)(bm + m) * K + k0 + k4);
            As[k4][m] = v.x; As[k4 + 1][m] = v.y; As[k4 + 2][m] = v.z; As[k4 + 3][m] = v.w;
        }
        for (int i = tid; i < BN * 4; i += 256) {
            int n = i >> 2, k4 = (i & 3) << 2;
            float4 v = *(const float4*)(Bm + (long)(bn + n) * K + k0 + k4);
            Bs[k4][n] = v.x; Bs[k4 + 1][n] = v.y; Bs[k4 + 2][n] = v.z; Bs[k4 + 3][n] = v.w;
        }
        __syncthreads();
#pragma unroll
        for (int kk = 0; kk < BK; ++kk) {
            float a[TM], b[TN];
#pragma unroll
            for (int i = 0; i < TM; i++) a[i] = As[kk][tr * TM + i];
#pragma unroll
            for (int j = 0; j < TN; j++) b[j] = Bs[kk][tc * TN + j];
#pragma unroll
            for (int i = 0; i < TM; i++)
#pragma unroll
                for (int j = 0; j < TN; j++) acc[i][j] += a[i] * b[j];
        }
        __syncthreads();
    }
#pragma unroll
    for (int i = 0; i < TM; i++) {
        int m = bm + tr * TM + i;
#pragma unroll
        for (int j = 0; j < TN; j++) {
            int n = bn + tc * TN + j;
            C[(long)m * N + n] = acc[i][j];
        }
    }
}

// ---------------------------------------------------------------------------
// fp32 GEMM C = A @ B (context = attn @ ctx), OT output.
// ---------------------------------------------------------------------------
template <int BM, int BN, int TM, int TN, typename OT>
__global__ __launch_bounds__(256) void gemm_bn(
    const float* __restrict__ A, const float* __restrict__ Bm, OT* __restrict__ C,
    int M, int N, int K, long sA, long sB, long sC)
{
    constexpr int BK = 16;
    __shared__ float As[BK][BM + 1];
    __shared__ float Bs[BK][BN + 1];
    const int z = blockIdx.z;
    A += (long)z * sA; Bm += (long)z * sB; C += (long)z * sC;
    const int bm = blockIdx.y * BM, bn = blockIdx.x * BN;
    const int tid = threadIdx.x;
    constexpr int TC = BN / TN;
    const int tc = tid % TC, tr = tid / TC;
    float acc[TM][TN] = {};
    for (int k0 = 0; k0 < K; k0 += BK) {
        for (int i = tid; i < BM * 4; i += 256) {
            int m = i >> 2, k4 = (i & 3) << 2;
            float4 v = *(const float4*)(A + (long)(bm + m) * K + k0 + k4);
            As[k4][m] = v.x; As[k4 + 1][m] = v.y; As[k4 + 2][m] = v.z; As[k4 + 3][m] = v.w;
        }
        for (int i = tid; i < BK * (BN / 4); i += 256) {
            int k = i / (BN / 4), n4 = (i % (BN / 4)) * 4;
            float4 v = *(const float4*)(Bm + (long)(k0 + k) * N + bn + n4);
            Bs[k][n4] = v.x; Bs[k][n4 + 1] = v.y; Bs[k][n4 + 2] = v.z; Bs[k][n4 + 3] = v.w;
        }
        __syncthreads();
#pragma unroll
        for (int kk = 0; kk < BK; ++kk) {
            float a[TM], b[TN];
#pragma unroll
            for (int i = 0; i < TM; i++) a[i] = As[kk][tr * TM + i];
#pragma unroll
            for (int j = 0; j < TN; j++) b[j] = Bs[kk][tc * TN + j];
#pragma unroll
            for (int i = 0; i < TM; i++)
#pragma unroll
                for (int j = 0; j < TN; j++) acc[i][j] += a[i] * b[j];
        }
        __syncthreads();
    }
#pragma unroll
    for (int i = 0; i < TM; i++) {
        int m = bm + tr * TM + i;
#pragma unroll
        for (int j = 0; j < TN; j++) {
            int n = bn + tc * TN + j;
            stout(&C[(long)m * N + n], acc[i][j]);
        }
    }
}

// ---------------------------------------------------------------------------
// Masked softmax over S=256, in place.
// ---------------------------------------------------------------------------
__global__ __launch_bounds__(256) void softmax_mask(
    float* __restrict__ attn, const int* __restrict__ src_len)
{
    __shared__ float red[4];
    const int b = blockIdx.y, t = blockIdx.x, s = threadIdx.x;
    float* row = attn + ((long)b * TT + t) * SS;
    const int L = src_len[b];
    float v = (s < L) ? row[s] : -INFINITY;
    float m = v;
#pragma unroll
    for (int o = 32; o >= 1; o >>= 1) m = fmaxf(m, __shfl_xor(m, o));
    if ((s & 63) == 0) red[s >> 6] = m;
    __syncthreads();
    m = fmaxf(fmaxf(red[0], red[1]), fmaxf(red[2], red[3]));
    __syncthreads();
    float e = (s < L) ? expf(v - m) : 0.0f;
    float sum = e;
#pragma unroll
    for (int o = 32; o >= 1; o >>= 1) sum += __shfl_xor(sum, o);
    if ((s & 63) == 0) red[s >> 6] = sum;
    __syncthreads();
    sum = red[0] + red[1] + red[2] + red[3];
    row[s] = e / sum;
}

// ---------------------------------------------------------------------------
extern "C" void kernel_launch(void* const* d_in, const int* in_sizes, int n_in,
                              void* d_out, int out_size, void* d_ws, size_t ws_size,
                              hipStream_t stream)
{
    const float* trg_emb = (const float*)d_in[0];
    const float* h0      = (const float*)d_in[1];
    const float* c0      = (const float*)d_in[2];
    const float* ctx     = (const float*)d_in[3];
    const int*   src_len = (const int*)d_in[4];
    const float* W_ih    = (const float*)d_in[5];
    const float* W_hh    = (const float*)d_in[6];
    const float* b_ih    = (const float*)d_in[7];
    const float* b_hh    = (const float*)d_in[8];
    const float* W_in    = (const float*)d_in[9];
    const float* W_out   = (const float*)d_in[10];

    float* out = (float*)d_out;
    float* h_tilde = out;                          // [B,T,H]
    float* hT = out + (size_t)BB * TT * HHH;       // [1,B,H]
    float* cT = hT + (size_t)BB * HHH;             // [1,B,H]

    char* w = (char*)d_ws;
    auto take = [&](size_t bytes) { void* p = w; w += (bytes + 255) & ~(size_t)255; return p; };
    u16* trg16  = (u16*)take(8388608ull * 2);
    u16* Wih16  = (u16*)take(4194304ull * 2);
    u16* Win16  = (u16*)take(1048576ull * 2);
    u16* Wout16 = (u16*)take(2097152ull * 2);
    u16* lstm16 = (u16*)take(8388608ull * 2);
    u16* Whi    = (u16*)take(4194304ull * 2);
    u16* Wlo    = (u16*)take(4194304ull * 2);
    u16* hEhi   = (u16*)take(65536ull * 2);
    u16* hElo   = (u16*)take(65536ull * 2);
    u16* hOhi   = (u16*)take(65536ull * 2);
    u16* hOlo   = (u16*)take(65536ull * 2);
    int* bar    = (int*)take(256);
    char* regionB = w;
    float* xgt = (float*)take(33554432ull * 4);    // [t][4H r=j*4+g][B] fp32
    float* q        = (float*)regionB;
    float* attn     = (float*)(regionB + 33554432ull);
    u16*   ctxout16 = (u16*)(regionB + 41943040ull);

    // barrier counter must start at 0 every call (ws is poisoned once)
    hipMemsetAsync(bar, 0, 256, stream);

    // prep (independent, parallel)
    f32_to_bf16<<<4096, 256, 0, stream>>>(trg_emb, trg16, 8388608);
    f32_to_bf16<<<2048, 256, 0, stream>>>(W_ih, Wih16, 4194304);
    f32_to_bf16<<<512, 256, 0, stream>>>(W_in, Win16, 1048576);
    f32_to_bf16<<<1024, 256, 0, stream>>>(W_out, Wout16, 2097152);
    split_whh<<<4096, 256, 0, stream>>>(W_hh, Whi, Wlo);
    h0_split<<<64, 256, 0, stream>>>(h0, hEhi, hElo);

    // x_gates = trg_emb @ W_ih^T + (b_ih+b_hh) -> fp32 xgt[t][j*4+g][b]
    gemm_mfma_bt<false, true, float><<<dim3(32, 64), 256, 0, stream>>>(
        trg16, trg16, Wih16, xgt, 8192, 4096, 1024, 1024, b_ih, b_hh);

    // persistent LSTM scan (single launch; writes lstm16, hT, cT)
    lstm_scan512<<<SCANBLK, 512, 0, stream>>>(xgt, Whi, Wlo, c0,
                                              hEhi, hElo, hOhi, hOlo,
                                              hT, cT, lstm16, bar);

    // q = lstm_out @ W_in^T (bf16 MFMA, fp32 out)
    gemm_mfma_bt<false, false, float><<<dim3(8, 64), 256, 0, stream>>>(
        lstm16, lstm16, Win16, q, 8192, 1024, 1024, 1024, nullptr, nullptr);

    // scores[b] = q[b] @ ctx[b]^T (fp32)
    gemm_bt<64, 64, 4, 4><<<dim3(4, 2, 64), 256, 0, stream>>>(
        q, ctx, attn, TT, SS, HHH,
        (long)TT * HHH, (long)SS * HHH, (long)TT * SS);

    softmax_mask<<<dim3(TT, BB, 1), 256, 0, stream>>>(attn, src_len);

    // context[b] = attn[b] @ ctx[b] (fp32 compute, bf16 out)
    gemm_bn<64, 64, 4, 4, u16><<<dim3(16, 2, 64), 256, 0, stream>>>(
        attn, ctx, ctxout16, TT, HHH, SS,
        (long)TT * SS, (long)SS * HHH, (long)TT * HHH);

    // h_tilde = tanh([context, lstm_out] @ W_out^T)
    gemm_mfma_bt<true, false, float><<<dim3(8, 64), 256, 0, stream>>>(
        ctxout16, lstm16, Wout16, h_tilde, 8192, 1024, 2048, 1024, nullptr, nullptr);
}